// Round 9
// baseline (81.988 us; speedup 1.0000x reference)
//
#include <hip/hip_runtime.h>
#include <hip/hip_bf16.h>

typedef __attribute__((ext_vector_type(8))) short short8;
typedef __attribute__((ext_vector_type(4))) float f32x4;

#define B_ 8
#define N_ 4096
#define E_ 16384
#define K_ 16
#define F_ 128

__device__ __forceinline__ float bf2f(unsigned short h) {
    unsigned int u = ((unsigned int)h) << 16;
    union { unsigned int u; float f; } c; c.u = u; return c.f;
}
__device__ __forceinline__ unsigned short f2bf(float f) {
    union { float f; unsigned int u; } c; c.f = f;
    unsigned int u = c.u;
    unsigned int r = (u + 0x7fffu + ((u >> 16) & 1u)) >> 16;
    return (unsigned short)r;
}
__device__ __forceinline__ float fast_tanh(float x) {
    float e = __expf(2.0f * x);
    return 1.0f - 2.0f / (e + 1.0f);
}

// ---- detect whether an "integer" input buffer is int64 (high words all 0) ----
__device__ __forceinline__ int detect64(const int* raw) {
    int o = 0;
    #pragma unroll
    for (int i = 1; i < 128; i += 2) o |= raw[i];
    return (o == 0) ? 1 : 0;
}

// One launch, partitioned grid:
//   blocks [0,512):     sender[i] = edges[b,e,0]        (handles i32/i64)
//   blocks [512,2560):  pne[i] = mask[i] ? ne[i] : -1   (handles i32/i64)
//   blocks [2560,2576): wf = W1,W2 in MFMA fragment order (bf16)
//     wf[((nt*4+g)*64+l)*8+t] = W[nt*16+(l&15)][g*32+8*(l>>4)+t]
__global__ void prep_idx(const int* __restrict__ edges_raw,
                         const int* __restrict__ ne_raw,
                         const int* __restrict__ mask,
                         const float* __restrict__ W1, const float* __restrict__ W2,
                         int* __restrict__ sender, int* __restrict__ pne,
                         unsigned short* __restrict__ wf) {
    int blk = blockIdx.x, tid = threadIdx.x;
    if (blk < 512) {
        __shared__ int s64;
        if (tid == 0) s64 = detect64(edges_raw);
        __syncthreads();
        int i = blk * 256 + tid;
        if (i < B_ * E_)
            sender[i] = s64 ? edges_raw[6 * (long long)i] : edges_raw[3 * (long long)i];
    } else if (blk < 2560) {
        __shared__ int s64;
        if (tid == 0) s64 = detect64(ne_raw);
        __syncthreads();
        int i = (blk - 512) * 256 + tid;
        if (i < B_ * N_ * K_) {
            int eid = s64 ? ne_raw[2 * (long long)i] : ne_raw[i];
            pne[i] = mask[i] ? eid : -1;
        }
    } else {
        int gtid = (blk - 2560) * 256 + tid;   // 0..4095
        int wsel = gtid >> 11;
        int q = gtid & 2047;
        int lane = q & 63;
        int gq = q >> 6;
        int nt = gq >> 2, g = gq & 3;
        const float* W = wsel ? W2 : W1;
        int j = nt * 16 + (lane & 15);
        int kbase = g * 32 + 8 * (lane >> 4);
        unsigned short* d = wf + wsel * 16384 + q * 8;
        #pragma unroll
        for (int t = 0; t < 8; ++t) d[t] = f2bf(W[j * 128 + kbase + t]);
    }
}

// edge_emb[b,e,:] = bf16( tanh( x[b,sender(e),:] @ W^T + bias ) )
// 64 edges/block, 4 waves. A=W (from wf), B=x^T -> D[j][edge];
// XCD-swizzled blocks: XCD x processes only batch x (B_ == 8 XCDs) so all
// x-row gathers stay in that XCD's L2.
template <int SRC32>
__global__ void __launch_bounds__(256) edge_kernel(
    const void* __restrict__ xsrc, const int* __restrict__ sender,
    const unsigned short* __restrict__ wf, const float* __restrict__ bias,
    unsigned short* __restrict__ eout) {
    __shared__ short xt[64 * F_];   // 16 KB, chunk-swizzled
    __shared__ int sids[64];
    int tid = threadIdx.x;
    int swz = (blockIdx.x & 7) * 256 + (blockIdx.x >> 3);   // batch-per-XCD
    int b = swz >> 8;
    int e0 = (swz & 255) * 64;
    if (tid < 64) sids[tid] = sender[b * E_ + e0 + tid];
    __syncthreads();
    // stage 64 rows into LDS as bf16; 16B chunks, pch = ch ^ (row&15)
    #pragma unroll
    for (int c = 0; c < 4; ++c) {
        int ci = tid + 256 * c;         // 0..1023
        int row = ci >> 4, ch = ci & 15;
        int pch = ch ^ (row & 15);
        if (SRC32) {
            const float* src = (const float*)xsrc + ((long long)(b * N_ + sids[row])) * F_ + ch * 8;
            float4 v0 = *(const float4*)src;
            float4 v1 = *(const float4*)(src + 4);
            ushort4 h0, h1;
            h0.x = f2bf(v0.x); h0.y = f2bf(v0.y); h0.z = f2bf(v0.z); h0.w = f2bf(v0.w);
            h1.x = f2bf(v1.x); h1.y = f2bf(v1.y); h1.z = f2bf(v1.z); h1.w = f2bf(v1.w);
            *(ushort4*)&xt[row * F_ + pch * 8] = h0;
            *(ushort4*)&xt[row * F_ + pch * 8 + 4] = h1;
        } else {
            const int4* src = (const int4*)((const unsigned short*)xsrc +
                                ((long long)(b * N_ + sids[row])) * F_ + ch * 8);
            *(int4*)&xt[row * F_ + pch * 8] = *src;
        }
    }
    __syncthreads();
    int w = tid >> 6, lane = tid & 63;
    int erow = w * 16 + (lane & 15);      // this wave's 16 edges
    short8 bfr[4];
    #pragma unroll
    for (int g = 0; g < 4; ++g) {
        int pch = (g * 4 + (lane >> 4)) ^ (erow & 15);
        bfr[g] = *(const short8*)&xt[erow * F_ + pch * 8];
    }
    int jq = (lane >> 4) * 4;             // j sub-offset of this lane's 4 regs
    long long ebase = ((long long)(b * E_ + e0 + w * 16 + (lane & 15))) * F_;
    #pragma unroll
    for (int nt = 0; nt < 8; ++nt) {
        f32x4 acc = (f32x4){0.f, 0.f, 0.f, 0.f};
        #pragma unroll
        for (int g = 0; g < 4; ++g) {
            short8 afr = *(const short8*)(wf + ((nt * 4 + g) * 64 + lane) * 8);
            acc = __builtin_amdgcn_mfma_f32_16x16x32_bf16(afr, bfr[g], acc, 0, 0, 0);
        }
        float4 bv = *(const float4*)(bias + nt * 16 + jq);
        ushort4 o;
        o.x = f2bf(fast_tanh(acc[0] + bv.x));
        o.y = f2bf(fast_tanh(acc[1] + bv.y));
        o.z = f2bf(fast_tanh(acc[2] + bv.z));
        o.w = f2bf(fast_tanh(acc[3] + bv.w));
        *(ushort4*)(eout + ebase + nt * 16 + jq) = o;
    }
}

// x_next[b,n,:] = sum_k mask * edge_emb[b, ne[n,k], :] / (cnt + eps)
// ONE node per 16-lane quarter (4 nodes/wave, 16/block): each lane owns 8
// cols (16B bf16) and loops over all 16 k's itself -> 16 independent 16B
// gathers in flight, NO cross-lane reduce; every lane stores its 8 cols.
// Index int4s are identical across the quarter -> L1 broadcast.
// XCD-swizzled: XCD x processes only batch x -> ebuf gathers L2-local.
__global__ void __launch_bounds__(256) agg_kernel(
    const unsigned short* __restrict__ ee, const int* __restrict__ pne,
    const float* __restrict__ x0, float* __restrict__ out,
    unsigned short* __restrict__ xbn, int col_off) {
    int tid = threadIdx.x;
    int swz = (blockIdx.x & 7) * 256 + (blockIdx.x >> 3);   // batch-per-XCD
    int nodeblk = swz * 16;            // 16 nodes per block
    int wid = tid >> 6, lane = tid & 63;
    int qt = lane >> 4, s16 = lane & 15;
    int node = nodeblk + wid * 4 + qt;
    int b = node >> 12;                // N=4096
    if (x0) {                          // copy 16 x0 rows -> out cols 0:128
        long long flat = (long long)nodeblk * F_ + tid * 8;
        int nn = tid >> 4;             // tid*8 / 128
        int j = (tid * 8) & 127;
        f32x4 c0 = *(const f32x4*)(x0 + flat);
        f32x4 c1 = *(const f32x4*)(x0 + flat + 4);
        float* od = out + (long long)(nodeblk + nn) * 384 + j;
        *(f32x4*)od = c0;
        *(f32x4*)(od + 4) = c1;
    }
    const int4* ip = (const int4*)(pne + node * K_);
    int4 i0 = ip[0], i1 = ip[1], i2 = ip[2], i3 = ip[3];
    float cnt = (float)((i0.x >= 0) + (i0.y >= 0) + (i0.z >= 0) + (i0.w >= 0) +
                        (i1.x >= 0) + (i1.y >= 0) + (i1.z >= 0) + (i1.w >= 0) +
                        (i2.x >= 0) + (i2.y >= 0) + (i2.z >= 0) + (i2.w >= 0) +
                        (i3.x >= 0) + (i3.y >= 0) + (i3.z >= 0) + (i3.w >= 0));
    const unsigned short* ebase = ee + (long long)b * (E_ * F_) + s16 * 8;
    float a0 = 0.f, a1 = 0.f, a2 = 0.f, a3 = 0.f;
    float a4 = 0.f, a5 = 0.f, a6 = 0.f, a7 = 0.f;
    #define PROC(pk) { \
        float m = ((pk) >= 0) ? 1.0f : 0.0f; \
        int eid = (pk) < 0 ? 0 : (pk); \
        short8 v = *(const short8*)(ebase + (long long)eid * F_); \
        a0 += m * bf2f((unsigned short)v[0]); a1 += m * bf2f((unsigned short)v[1]); \
        a2 += m * bf2f((unsigned short)v[2]); a3 += m * bf2f((unsigned short)v[3]); \
        a4 += m * bf2f((unsigned short)v[4]); a5 += m * bf2f((unsigned short)v[5]); \
        a6 += m * bf2f((unsigned short)v[6]); a7 += m * bf2f((unsigned short)v[7]); }
    PROC(i0.x) PROC(i0.y) PROC(i0.z) PROC(i0.w)
    PROC(i1.x) PROC(i1.y) PROC(i1.z) PROC(i1.w)
    PROC(i2.x) PROC(i2.y) PROC(i2.z) PROC(i2.w)
    PROC(i3.x) PROC(i3.y) PROC(i3.z) PROC(i3.w)
    #undef PROC
    float inv = 1.0f / (cnt + 1e-8f);
    a0 *= inv; a1 *= inv; a2 *= inv; a3 *= inv;
    a4 *= inv; a5 *= inv; a6 *= inv; a7 *= inv;
    float* po = out + (long long)node * 384 + col_off + s16 * 8;
    f32x4 o0 = (f32x4){a0, a1, a2, a3};
    f32x4 o1 = (f32x4){a4, a5, a6, a7};
    *(f32x4*)po = o0;
    *(f32x4*)(po + 4) = o1;
    if (xbn) {
        short8 h;
        h[0] = (short)f2bf(a0); h[1] = (short)f2bf(a1);
        h[2] = (short)f2bf(a2); h[3] = (short)f2bf(a3);
        h[4] = (short)f2bf(a4); h[5] = (short)f2bf(a5);
        h[6] = (short)f2bf(a6); h[7] = (short)f2bf(a7);
        *(short8*)(xbn + (long long)node * F_ + s16 * 8) = h;
    }
}

extern "C" void kernel_launch(void* const* d_in, const int* in_sizes, int n_in,
                              void* d_out, int out_size, void* d_ws, size_t ws_size,
                              hipStream_t stream) {
    const float* x0        = (const float*)d_in[0];
    const int*   edges_raw = (const int*)d_in[1];
    const int*   ne_raw    = (const int*)d_in[2];
    const int*   mask      = (const int*)d_in[3];
    const float* W1        = (const float*)d_in[4];
    const float* b1        = (const float*)d_in[5];
    const float* W2        = (const float*)d_in[6];
    const float* b2        = (const float*)d_in[7];
    float* out = (float*)d_out;
    char* ws = (char*)d_ws;

    unsigned short* ebuf = (unsigned short*)ws;                   // B*E*F bf16 = 32 MB
    unsigned short* x1b  = (unsigned short*)(ws + 33554432);      // B*N*F bf16 = 8 MB
    unsigned short* wf   = (unsigned short*)(ws + 41943040);      // 2*128*128  = 64 KB
    int* sender32        = (int*)(ws + 42008576);                 // B*E int32  = 512 KB
    int* pne             = (int*)(ws + 42532864);                 // B*N*K      = 2 MB

    prep_idx<<<2576, 256, 0, stream>>>(edges_raw, ne_raw, mask, W1, W2,
                                       sender32, pne, wf);
    // round 1: edge transform from fp32 x0; agg also copies x0 -> out[:,0:128]
    edge_kernel<1><<<2048, 256, 0, stream>>>(x0, sender32, wf, b1, ebuf);
    agg_kernel<<<2048, 256, 0, stream>>>(ebuf, pne, x0, out, x1b, 128);
    // round 2
    edge_kernel<0><<<2048, 256, 0, stream>>>(x1b, sender32, wf + 16384, b2, ebuf);
    agg_kernel<<<2048, 256, 0, stream>>>(ebuf, pne, nullptr, out, nullptr, 256);
}

// Round 10
// 75.471 us; speedup vs baseline: 1.0863x; 1.0863x over previous
//
#include <hip/hip_runtime.h>
#include <hip/hip_bf16.h>

typedef __attribute__((ext_vector_type(8))) short short8;
typedef __attribute__((ext_vector_type(4))) float f32x4;
typedef __attribute__((ext_vector_type(2))) float f32x2;

#define B_ 8
#define N_ 4096
#define E_ 16384
#define K_ 16
#define F_ 128

#if defined(__has_builtin)
#  if __has_builtin(__builtin_amdgcn_cvt_pk_f32_fp8) && __has_builtin(__builtin_amdgcn_cvt_pk_fp8_f32)
#    define HW_FP8 1
#  endif
#endif

__device__ __forceinline__ float bf2f(unsigned short h) {
    unsigned int u = ((unsigned int)h) << 16;
    union { unsigned int u; float f; } c; c.u = u; return c.f;
}
__device__ __forceinline__ unsigned short f2bf(float f) {
    union { float f; unsigned int u; } c; c.f = f;
    unsigned int u = c.u;
    unsigned int r = (u + 0x7fffu + ((u >> 16) & 1u)) >> 16;
    return (unsigned short)r;
}
__device__ __forceinline__ float fast_tanh(float x) {
    float e = __expf(2.0f * x);
    return 1.0f - 2.0f / (e + 1.0f);
}

// ---- fp8 e4m3fn helpers (HW cvt when available; exact manual fallback) ----
__device__ __forceinline__ unsigned int f2fp8_manual(float v) {
    // |v| <= 1.0 guaranteed (tanh). RNE via add-with-carry on f32 bits.
    unsigned int u = __float_as_uint(v * 0x1p-120f);
    unsigned int r = (u & 0x7fffffffu) + 0x7ffffu + ((u >> 20) & 1u);
    return ((r >> 20) & 0x7fu) | ((u >> 24) & 0x80u);
}
__device__ __forceinline__ unsigned int pack_fp8x4(float t0, float t1, float t2, float t3) {
#ifdef HW_FP8
    int wd = 0;
    wd = __builtin_amdgcn_cvt_pk_fp8_f32(t0, t1, wd, false);
    wd = __builtin_amdgcn_cvt_pk_fp8_f32(t2, t3, wd, true);
    return (unsigned int)wd;
#else
    return f2fp8_manual(t0) | (f2fp8_manual(t1) << 8) |
           (f2fp8_manual(t2) << 16) | (f2fp8_manual(t3) << 24);
#endif
}

// ---- detect whether an "integer" input buffer is int64 (high words all 0) ----
__device__ __forceinline__ int detect64(const int* raw) {
    int o = 0;
    #pragma unroll
    for (int i = 1; i < 128; i += 2) o |= raw[i];
    return (o == 0) ? 1 : 0;
}

// One launch, partitioned grid:
//   blocks [0,512):     sender[i] = edges[b,e,0]        (handles i32/i64)
//   blocks [512,2560):  pne[i] = mask[i] ? ne[i] : -1   (handles i32/i64)
//   blocks [2560,2576): wf = W1,W2 in MFMA fragment order (bf16)
__global__ void prep_idx(const int* __restrict__ edges_raw,
                         const int* __restrict__ ne_raw,
                         const int* __restrict__ mask,
                         const float* __restrict__ W1, const float* __restrict__ W2,
                         int* __restrict__ sender, int* __restrict__ pne,
                         unsigned short* __restrict__ wf) {
    int blk = blockIdx.x, tid = threadIdx.x;
    if (blk < 512) {
        __shared__ int s64;
        if (tid == 0) s64 = detect64(edges_raw);
        __syncthreads();
        int i = blk * 256 + tid;
        if (i < B_ * E_)
            sender[i] = s64 ? edges_raw[6 * (long long)i] : edges_raw[3 * (long long)i];
    } else if (blk < 2560) {
        __shared__ int s64;
        if (tid == 0) s64 = detect64(ne_raw);
        __syncthreads();
        int i = (blk - 512) * 256 + tid;
        if (i < B_ * N_ * K_) {
            int eid = s64 ? ne_raw[2 * (long long)i] : ne_raw[i];
            pne[i] = mask[i] ? eid : -1;
        }
    } else {
        int gtid = (blk - 2560) * 256 + tid;   // 0..4095
        int wsel = gtid >> 11;
        int q = gtid & 2047;
        int lane = q & 63;
        int gq = q >> 6;
        int nt = gq >> 2, g = gq & 3;
        const float* W = wsel ? W2 : W1;
        int j = nt * 16 + (lane & 15);
        int kbase = g * 32 + 8 * (lane >> 4);
        unsigned short* d = wf + wsel * 16384 + q * 8;
        #pragma unroll
        for (int t = 0; t < 8; ++t) d[t] = f2bf(W[j * 128 + kbase + t]);
    }
}

// edge_emb[b,e,:] = fp8( tanh( x[b,sender(e),:] @ W^T + bias ) )
// 64 edges/block, 4 waves. A=W (from wf), B=x^T -> D[j][edge];
// XCD-swizzled blocks: XCD x processes only batch x.
template <int SRC32>
__global__ void __launch_bounds__(256) edge_kernel(
    const void* __restrict__ xsrc, const int* __restrict__ sender,
    const unsigned short* __restrict__ wf, const float* __restrict__ bias,
    unsigned char* __restrict__ eout) {
    __shared__ short xt[64 * F_];   // 16 KB, chunk-swizzled
    __shared__ int sids[64];
    int tid = threadIdx.x;
    int swz = (blockIdx.x & 7) * 256 + (blockIdx.x >> 3);   // batch-per-XCD
    int b = swz >> 8;
    int e0 = (swz & 255) * 64;
    if (tid < 64) sids[tid] = sender[b * E_ + e0 + tid];
    __syncthreads();
    // stage 64 rows into LDS as bf16; 16B chunks, pch = ch ^ (row&15)
    #pragma unroll
    for (int c = 0; c < 4; ++c) {
        int ci = tid + 256 * c;         // 0..1023
        int row = ci >> 4, ch = ci & 15;
        int pch = ch ^ (row & 15);
        if (SRC32) {
            const float* src = (const float*)xsrc + ((long long)(b * N_ + sids[row])) * F_ + ch * 8;
            float4 v0 = *(const float4*)src;
            float4 v1 = *(const float4*)(src + 4);
            ushort4 h0, h1;
            h0.x = f2bf(v0.x); h0.y = f2bf(v0.y); h0.z = f2bf(v0.z); h0.w = f2bf(v0.w);
            h1.x = f2bf(v1.x); h1.y = f2bf(v1.y); h1.z = f2bf(v1.z); h1.w = f2bf(v1.w);
            *(ushort4*)&xt[row * F_ + pch * 8] = h0;
            *(ushort4*)&xt[row * F_ + pch * 8 + 4] = h1;
        } else {
            const int4* src = (const int4*)((const unsigned short*)xsrc +
                                ((long long)(b * N_ + sids[row])) * F_ + ch * 8);
            *(int4*)&xt[row * F_ + pch * 8] = *src;
        }
    }
    __syncthreads();
    int w = tid >> 6, lane = tid & 63;
    int erow = w * 16 + (lane & 15);      // this wave's 16 edges
    short8 bfr[4];
    #pragma unroll
    for (int g = 0; g < 4; ++g) {
        int pch = (g * 4 + (lane >> 4)) ^ (erow & 15);
        bfr[g] = *(const short8*)&xt[erow * F_ + pch * 8];
    }
    int jq = (lane >> 4) * 4;             // j sub-offset of this lane's 4 regs
    long long ebyte = ((long long)(b * E_ + e0 + w * 16 + (lane & 15))) * F_;  // bytes (fp8 row = 128B)
    #pragma unroll
    for (int nt = 0; nt < 8; ++nt) {
        f32x4 acc = (f32x4){0.f, 0.f, 0.f, 0.f};
        #pragma unroll
        for (int g = 0; g < 4; ++g) {
            short8 afr = *(const short8*)(wf + ((nt * 4 + g) * 64 + lane) * 8);
            acc = __builtin_amdgcn_mfma_f32_16x16x32_bf16(afr, bfr[g], acc, 0, 0, 0);
        }
        float4 bv = *(const float4*)(bias + nt * 16 + jq);
        float t0 = fast_tanh(acc[0] + bv.x);
        float t1 = fast_tanh(acc[1] + bv.y);
        float t2 = fast_tanh(acc[2] + bv.z);
        float t3 = fast_tanh(acc[3] + bv.w);
        *(unsigned int*)(eout + ebyte + nt * 16 + jq) = pack_fp8x4(t0, t1, t2, t3);
    }
}

// x_next[b,n,:] = sum_k mask * edge_emb[b, ne[n,k], :] / (cnt + eps)
// ONE node per 16-lane quarter; lane owns 8 cols (8B fp8) and loops all 16 ks
// -> 16 independent 8B gathers in flight, no cross-lane reduce.
// fp8 ebuf slice = 2 MB/batch -> fully L2-resident per XCD.
__global__ void __launch_bounds__(256) agg_kernel(
    const unsigned char* __restrict__ ee, const int* __restrict__ pne,
    const float* __restrict__ x0, float* __restrict__ out,
    unsigned short* __restrict__ xbn, int col_off) {
    int tid = threadIdx.x;
    int swz = (blockIdx.x & 7) * 256 + (blockIdx.x >> 3);   // batch-per-XCD
    int nodeblk = swz * 16;            // 16 nodes per block
    int wid = tid >> 6, lane = tid & 63;
    int qt = lane >> 4, s16 = lane & 15;
    int node = nodeblk + wid * 4 + qt;
    int b = node >> 12;                // N=4096
    if (x0) {                          // copy 16 x0 rows -> out cols 0:128
        long long flat = (long long)nodeblk * F_ + tid * 8;
        int nn = tid >> 4;             // tid*8 / 128
        int j = (tid * 8) & 127;
        f32x4 c0 = *(const f32x4*)(x0 + flat);
        f32x4 c1 = *(const f32x4*)(x0 + flat + 4);
        float* od = out + (long long)(nodeblk + nn) * 384 + j;
        *(f32x4*)od = c0;
        *(f32x4*)(od + 4) = c1;
    }
    const int4* ip = (const int4*)(pne + node * K_);
    int4 i0 = ip[0], i1 = ip[1], i2 = ip[2], i3 = ip[3];
    float cnt = (float)((i0.x >= 0) + (i0.y >= 0) + (i0.z >= 0) + (i0.w >= 0) +
                        (i1.x >= 0) + (i1.y >= 0) + (i1.z >= 0) + (i1.w >= 0) +
                        (i2.x >= 0) + (i2.y >= 0) + (i2.z >= 0) + (i2.w >= 0) +
                        (i3.x >= 0) + (i3.y >= 0) + (i3.z >= 0) + (i3.w >= 0));
    const unsigned char* ebase = ee + (long long)b * (E_ * F_) + s16 * 8;
    float a0 = 0.f, a1 = 0.f, a2 = 0.f, a3 = 0.f;
    float a4 = 0.f, a5 = 0.f, a6 = 0.f, a7 = 0.f;
#ifdef HW_FP8
    #define PROC(pk) { \
        float m = ((pk) >= 0) ? 1.0f : 0.0f; \
        int eid = (pk) < 0 ? 0 : (pk); \
        uint2 v = *(const uint2*)(ebase + (long long)eid * F_); \
        f32x2 c0 = __builtin_amdgcn_cvt_pk_f32_fp8(v.x, false); \
        f32x2 c1 = __builtin_amdgcn_cvt_pk_f32_fp8(v.x, true); \
        f32x2 c2 = __builtin_amdgcn_cvt_pk_f32_fp8(v.y, false); \
        f32x2 c3 = __builtin_amdgcn_cvt_pk_f32_fp8(v.y, true); \
        a0 += m * c0.x; a1 += m * c0.y; a2 += m * c1.x; a3 += m * c1.y; \
        a4 += m * c2.x; a5 += m * c2.y; a6 += m * c3.x; a7 += m * c3.y; }
#else
    // value = bitcast((b&0x80)<<24 | (b&0x7f)<<20) * 2^120; scale folded into ms
    #define DEC(bb) __int_as_float((int)((((bb) & 0x80u) << 24) | (((bb) & 0x7fu) << 20)))
    #define PROC(pk) { \
        float ms = ((pk) >= 0) ? 0x1p120f : 0.0f; \
        int eid = (pk) < 0 ? 0 : (pk); \
        uint2 v = *(const uint2*)(ebase + (long long)eid * F_); \
        a0 += ms * DEC(v.x); a1 += ms * DEC(v.x >> 8); \
        a2 += ms * DEC(v.x >> 16); a3 += ms * DEC(v.x >> 24); \
        a4 += ms * DEC(v.y); a5 += ms * DEC(v.y >> 8); \
        a6 += ms * DEC(v.y >> 16); a7 += ms * DEC(v.y >> 24); }
#endif
    PROC(i0.x) PROC(i0.y) PROC(i0.z) PROC(i0.w)
    PROC(i1.x) PROC(i1.y) PROC(i1.z) PROC(i1.w)
    PROC(i2.x) PROC(i2.y) PROC(i2.z) PROC(i2.w)
    PROC(i3.x) PROC(i3.y) PROC(i3.z) PROC(i3.w)
    #undef PROC
    float inv = 1.0f / (cnt + 1e-8f);
    a0 *= inv; a1 *= inv; a2 *= inv; a3 *= inv;
    a4 *= inv; a5 *= inv; a6 *= inv; a7 *= inv;
    float* po = out + (long long)node * 384 + col_off + s16 * 8;
    f32x4 o0 = (f32x4){a0, a1, a2, a3};
    f32x4 o1 = (f32x4){a4, a5, a6, a7};
    *(f32x4*)po = o0;
    *(f32x4*)(po + 4) = o1;
    if (xbn) {
        short8 h;
        h[0] = (short)f2bf(a0); h[1] = (short)f2bf(a1);
        h[2] = (short)f2bf(a2); h[3] = (short)f2bf(a3);
        h[4] = (short)f2bf(a4); h[5] = (short)f2bf(a5);
        h[6] = (short)f2bf(a6); h[7] = (short)f2bf(a7);
        *(short8*)(xbn + (long long)node * F_ + s16 * 8) = h;
    }
}

extern "C" void kernel_launch(void* const* d_in, const int* in_sizes, int n_in,
                              void* d_out, int out_size, void* d_ws, size_t ws_size,
                              hipStream_t stream) {
    const float* x0        = (const float*)d_in[0];
    const int*   edges_raw = (const int*)d_in[1];
    const int*   ne_raw    = (const int*)d_in[2];
    const int*   mask      = (const int*)d_in[3];
    const float* W1        = (const float*)d_in[4];
    const float* b1        = (const float*)d_in[5];
    const float* W2        = (const float*)d_in[6];
    const float* b2        = (const float*)d_in[7];
    float* out = (float*)d_out;
    char* ws = (char*)d_ws;

    unsigned char*  ebuf = (unsigned char*)ws;                    // B*E*F fp8  = 16 MB
    unsigned short* x1b  = (unsigned short*)(ws + 16777216);      // B*N*F bf16 = 8 MB
    unsigned short* wf   = (unsigned short*)(ws + 25165824);      // 2*128*128  = 64 KB
    int* sender32        = (int*)(ws + 25231360);                 // B*E int32  = 512 KB
    int* pne             = (int*)(ws + 25755648);                 // B*N*K      = 2 MB

    prep_idx<<<2576, 256, 0, stream>>>(edges_raw, ne_raw, mask, W1, W2,
                                       sender32, pne, wf);
    // round 1: edge transform from fp32 x0; agg also copies x0 -> out[:,0:128]
    edge_kernel<1><<<2048, 256, 0, stream>>>(x0, sender32, wf, b1, ebuf);
    agg_kernel<<<2048, 256, 0, stream>>>(ebuf, pne, x0, out, x1b, 128);
    // round 2
    edge_kernel<0><<<2048, 256, 0, stream>>>(x1b, sender32, wf + 16384, b2, ebuf);
    agg_kernel<<<2048, 256, 0, stream>>>(ebuf, pne, nullptr, out, nullptr, 256);
}